// Round 10
// baseline (177.655 us; speedup 1.0000x reference)
//
#include <hip/hip_runtime.h>
#include <hip/hip_bf16.h>
#include <math.h>

#define Bsz 4
#define Nseq 2048
#define Dm 256
#define Hh 8
#define Hd 32
#define EPS_ 1e-5f
#define SCALE_ 0.17677669529663687f               // 1/sqrt(32)
#define QSC_ (0.17677669529663687f * 1.4426950408889634f)  // fold log2(e) for exp2

typedef __attribute__((ext_vector_type(8))) short short8;
typedef __attribute__((ext_vector_type(4))) short short4v;
typedef __attribute__((ext_vector_type(4))) float f32x4;
typedef __attribute__((ext_vector_type(16))) float f32x16;

// async global->LDS, 16B per lane. LDS dest = wave-uniform base + lane*16.
__device__ __forceinline__ void gload16(const void* g, void* l) {
    __builtin_amdgcn_global_load_lds(
        (const __attribute__((address_space(1))) void*)g,
        (__attribute__((address_space(3))) void*)l, 16, 0, 0);
}

__device__ __forceinline__ short bf16s(float f) {
    __hip_bfloat16 h = __float2bfloat16(f);
    return *(short*)&h;
}

union FU { float f; unsigned u; };

// pack two fp32 -> (bf16(a) | bf16(b)<<16) via single v_perm_b32 (truncation)
__device__ __forceinline__ int pk2bf(float a, float b) {
    FU ua, ub; ua.f = a; ub.f = b;
    return (int)__builtin_amdgcn_perm(ub.u, ua.u, 0x07060302u);
}

union I4S8 { int i[4]; short8 s; };

// ---------------- prep: LN1 (bid<2048) + weight transpose (bid>=2048) ------
__global__ __launch_bounds__(256) void prep_kernel(
    const float* __restrict__ x, const float* __restrict__ g1,
    const float* __restrict__ b1v, __hip_bfloat16* __restrict__ hout,
    const float* __restrict__ s0, const float* __restrict__ s1,
    const float* __restrict__ s2, const float* __restrict__ s3,
    __hip_bfloat16* __restrict__ d0, __hip_bfloat16* __restrict__ d1,
    __hip_bfloat16* __restrict__ d2, __hip_bfloat16* __restrict__ d3) {
    __shared__ float t[32][33];
    if (blockIdx.x < 2048) {
        int row  = blockIdx.x * 4 + (threadIdx.x >> 6);
        int lane = threadIdx.x & 63;
        const float* xr = x + (size_t)row * Dm;
        float4 v = *(const float4*)(xr + lane * 4);
        float s  = v.x + v.y + v.z + v.w;
        float ss = v.x * v.x + v.y * v.y + v.z * v.z + v.w * v.w;
        #pragma unroll
        for (int off = 32; off; off >>= 1) {
            s  += __shfl_xor(s, off);
            ss += __shfl_xor(ss, off);
        }
        float mu  = s * (1.0f / Dm);
        float var = ss * (1.0f / Dm) - mu * mu;
        float rs  = rsqrtf(var + EPS_);
        float4 gv = *(const float4*)(g1 + lane * 4);
        float4 bv = *(const float4*)(b1v + lane * 4);
        short4v o4 = { bf16s((v.x - mu) * rs * gv.x + bv.x),
                       bf16s((v.y - mu) * rs * gv.y + bv.y),
                       bf16s((v.z - mu) * rs * gv.z + bv.z),
                       bf16s((v.w - mu) * rs * gv.w + bv.w) };
        *(short4v*)(hout + (size_t)row * Dm + lane * 4) = o4;
        return;
    }
    int bid = blockIdx.x - 2048;
    const float* src; __hip_bfloat16* dst; int K, N, tb;
    if (bid < 192)      { src = s0; dst = d0; K = 256; N = 768; tb = bid; }
    else if (bid < 256) { src = s1; dst = d1; K = 256; N = 256; tb = bid - 192; }
    else if (bid < 384) { src = s2; dst = d2; K = 256; N = 512; tb = bid - 256; }
    else                { src = s3; dst = d3; K = 512; N = 256; tb = bid - 384; }
    int tn = N >> 5;
    int k0 = (tb / tn) * 32, n0 = (tb % tn) * 32;
    int c = threadIdx.x & 31, r0 = threadIdx.x >> 5;
    #pragma unroll
    for (int i = 0; i < 4; i++) {
        int r = r0 + i * 8;
        t[r][c] = src[(size_t)(k0 + r) * N + n0 + c];
    }
    __syncthreads();
    #pragma unroll
    for (int i = 0; i < 4; i++) {
        int n = r0 + i * 8;
        dst[(size_t)(n0 + n) * K + k0 + c] = __float2bfloat16(t[c][n]);
    }
}

// ---------------- QKV: BK=64 dbuf MFMA GEMM + bias/RoPE/scatter ------------
__global__ __launch_bounds__(256) void qkv_mfma(const __hip_bfloat16* __restrict__ A,
                                                const __hip_bfloat16* __restrict__ Wt,
                                                const float* __restrict__ bias,
                                                const float* __restrict__ fcos,
                                                const float* __restrict__ fsin,
                                                __hip_bfloat16* __restrict__ qout,
                                                __hip_bfloat16* __restrict__ kout,
                                                __hip_bfloat16* __restrict__ vt) {
    const int K = 256;
    __shared__ __align__(16) __hip_bfloat16 As[2][64 * 64];
    __shared__ __align__(16) __hip_bfloat16 Bs[2][64 * 64];
    const int tid = threadIdx.x, w = tid >> 6, lane = tid & 63;
    const int lm = lane & 15, lq = lane >> 4;
    const int bm = blockIdx.y * 64, bn = blockIdx.x * 64;
    f32x4 acc[4];
    #pragma unroll
    for (int j = 0; j < 4; j++) acc[j] = (f32x4){0.f, 0.f, 0.f, 0.f};

    const int sr = tid >> 3, ssl = tid & 7;
    const int sgk = (ssl ^ (sr & 7)) * 8;
    const int sr2 = 32 + sr;
    const int sgk2 = (ssl ^ (sr2 & 7)) * 8;

    gload16(A + (size_t)(bm + sr) * K + sgk, &As[0][w * 512]);
    gload16(A + (size_t)(bm + sr2) * K + sgk2, &As[0][2048 + w * 512]);
    gload16(Wt + (size_t)(bn + sr) * K + sgk, &Bs[0][w * 512]);
    gload16(Wt + (size_t)(bn + sr2) * K + sgk2, &Bs[0][2048 + w * 512]);

    const int arow = w * 16 + lm;
    const int ar7 = arow & 7;
    for (int t = 0; t < K / 64; t++) {
        const int buf = t & 1;
        __syncthreads();
        if (t + 1 < K / 64) {
            int k0 = (t + 1) * 64;
            gload16(A + (size_t)(bm + sr) * K + k0 + sgk, &As[buf ^ 1][w * 512]);
            gload16(A + (size_t)(bm + sr2) * K + k0 + sgk2, &As[buf ^ 1][2048 + w * 512]);
            gload16(Wt + (size_t)(bn + sr) * K + k0 + sgk, &Bs[buf ^ 1][w * 512]);
            gload16(Wt + (size_t)(bn + sr2) * K + k0 + sgk2, &Bs[buf ^ 1][2048 + w * 512]);
        }
        #pragma unroll
        for (int ks = 0; ks < 2; ks++) {
            short8 a = *(const short8*)&As[buf][arow * 64 + (((ks * 4 + lq) ^ ar7) * 8)];
            #pragma unroll
            for (int nf = 0; nf < 4; nf++) {
                int cc = nf * 16 + lm;
                short8 bfr = *(const short8*)&Bs[buf][cc * 64 + (((ks * 4 + lq) ^ (cc & 7)) * 8)];
                acc[nf] = __builtin_amdgcn_mfma_f32_16x16x32_bf16(a, bfr, acc[nf], 0, 0, 0);
            }
        }
    }
    const int seg = bn >> 8;  // 0=q 1=k 2=v, uniform per block
    #pragma unroll
    for (int nf = 0; nf < 4; nf++) {
        int cg = bn + nf * 16 + lm;
        int hh = (cg & 255) >> 5;
        int dd = (nf & 1) * 16 + lm;
        int i0 = dd >> 1;
        float bi = bias[cg];
        #pragma unroll
        for (int r = 0; r < 4; r++) {
            int rg = bm + w * 16 + lq * 4 + r;
            int bb = rg >> 11, n = rg & (Nseq - 1);
            float v = acc[nf][r] + bi;
            if (seg == 2) {
                vt[(((size_t)(bb * Hh + hh)) * Hd + dd) * Nseq + n] = __float2bfloat16(v);
            } else {
                float vp = __shfl_xor(v, 1);
                float cs = fcos[n * 16 + i0], sn = fsin[n * 16 + i0];
                float outv = (dd & 1) ? (vp * sn + v * cs) : (v * cs - vp * sn);
                if (seg == 0) outv *= QSC_;
                __hip_bfloat16* dst = (seg == 0) ? qout : kout;
                dst[(((size_t)(bb * Hh + hh)) * Nseq + n) * Hd + dd] = __float2bfloat16(outv);
            }
        }
    }
}

// ---------------- Flash attention: all-register K-loop, zero in-loop LDS ---
// Block = 64 q rows, 4 waves = 2 q-groups x 2 key-halves; wave handles 32q x
// 1024 keys. Q, K, AND V fragments load straight from global into registers:
// with vt[B,H,d,N], the PV B-frag lane mapping (n=l31, k=hi*8+j) is 16
// contiguous bytes along keys; K/Q A/B-frags are 16B along d. One-chunk
// register prefetch; compiler vmcnt waits are the only sync. LDS used only
// for the final cross-parity reduction (8.7 KB).
__global__ __launch_bounds__(256) void attn_mfma(const __hip_bfloat16* __restrict__ q,
                                                 const __hip_bfloat16* __restrict__ k,
                                                 const __hip_bfloat16* __restrict__ vt,
                                                 __hip_bfloat16* __restrict__ att) {
    __shared__ float RedO[2048];   // 8 KB
    __shared__ float RedS[64];
    __shared__ float smS[64];

    const int tid = threadIdx.x, w = tid >> 6, lane = tid & 63;
    const int l31 = lane & 31, hi = lane >> 5;
    const int wq = w >> 1, wk = w & 1;
    const int bh = blockIdx.y, qbase = blockIdx.x * 64;
    const __hip_bfloat16* qp = q + ((size_t)bh * Nseq + qbase) * Hd;
    const __hip_bfloat16* kp = k + (size_t)bh * Nseq * Hd;
    const __hip_bfloat16* vp = vt + (size_t)bh * Hd * Nseq;

    // Q B-frags direct from global (q rows wq*32+l31, d halves)
    const __hip_bfloat16* qb2 = qp + (size_t)(wq * 32 + l31) * Hd + hi * 8;
    short8 qf0 = *(const short8*)(qb2);
    short8 qf1 = *(const short8*)(qb2 + 16);

    const __hip_bfloat16* kb = kp + (size_t)l31 * Hd + hi * 8;   // + chunk*2048
    const __hip_bfloat16* vb = vp + (size_t)l31 * Nseq + hi * 8; // + chunk*64

    // chunk wk -> regs
    short8 kf0 = *(const short8*)(kb + wk * 2048);
    short8 kf1 = *(const short8*)(kb + wk * 2048 + 16);
    short8 kf2 = *(const short8*)(kb + wk * 2048 + 1024);
    short8 kf3 = *(const short8*)(kb + wk * 2048 + 1040);
    short8 vf0 = *(const short8*)(vb + wk * 64);
    short8 vf1 = *(const short8*)(vb + wk * 64 + 16);
    short8 vf2 = *(const short8*)(vb + wk * 64 + 32);
    short8 vf3 = *(const short8*)(vb + wk * 64 + 48);

    f32x16 O;
    #pragma unroll
    for (int i = 0; i < 16; i++) O[i] = 0.f;
    float sm = 0.f;

    for (int t = 0; t < 16; t++) {
        short8 nk0, nk1, nk2, nk3, nv0, nv1, nv2, nv3;
        if (t + 1 < 16) {
            const int c = 2 * (t + 1) + wk;
            const __hip_bfloat16* kbn = kb + (size_t)c * 2048;
            const __hip_bfloat16* vbn = vb + c * 64;
            nk0 = *(const short8*)(kbn);
            nk1 = *(const short8*)(kbn + 16);
            nk2 = *(const short8*)(kbn + 1024);
            nk3 = *(const short8*)(kbn + 1040);
            nv0 = *(const short8*)(vbn);
            nv1 = *(const short8*)(vbn + 16);
            nv2 = *(const short8*)(vbn + 32);
            nv3 = *(const short8*)(vbn + 48);
        }
        // S^T = K·Q^T (keys 0-31 in St0, 32-63 in St1); all operands in regs
        f32x16 St0, St1;
        #pragma unroll
        for (int i = 0; i < 16; i++) { St0[i] = 0.f; St1[i] = 0.f; }
        St0 = __builtin_amdgcn_mfma_f32_32x32x16_bf16(kf0, qf0, St0, 0, 0, 0);
        St0 = __builtin_amdgcn_mfma_f32_32x32x16_bf16(kf1, qf1, St0, 0, 0, 0);
        St1 = __builtin_amdgcn_mfma_f32_32x32x16_bf16(kf2, qf0, St1, 0, 0, 0);
        St1 = __builtin_amdgcn_mfma_f32_32x32x16_bf16(kf3, qf1, St1, 0, 0, 0);
        // exp2 + single-instruction pair pack
        int pk0[8], pk1[8];
        #pragma unroll
        for (int p = 0; p < 8; p++) {
            float a = __builtin_amdgcn_exp2f(St0[2 * p]);
            float b = __builtin_amdgcn_exp2f(St0[2 * p + 1]);
            sm += a + b;
            pk0[p] = pk2bf(a, b);
        }
        #pragma unroll
        for (int p = 0; p < 8; p++) {
            float a = __builtin_amdgcn_exp2f(St1[2 * p]);
            float b = __builtin_amdgcn_exp2f(St1[2 * p + 1]);
            sm += a + b;
            pk1[p] = pk2bf(a, b);
        }
        // PV: per 16-key block tt, P A-frag via reg-select + half-swap
        #pragma unroll
        for (int tt = 0; tt < 4; tt++) {
            const int* PK = (tt >> 1) ? pk1 : pk0;
            const int base = 4 * (tt & 1);
            int keep0 = hi ? PK[base + 2] : PK[base + 0];
            int keep1 = hi ? PK[base + 3] : PK[base + 1];
            int send0 = hi ? PK[base + 0] : PK[base + 2];
            int send1 = hi ? PK[base + 1] : PK[base + 3];
            int x0 = __shfl_xor(send0, 32);
            int x1 = __shfl_xor(send1, 32);
            I4S8 u;
            u.i[0] = hi ? x0 : keep0;
            u.i[1] = hi ? x1 : keep1;
            u.i[2] = hi ? keep0 : x0;
            u.i[3] = hi ? keep1 : x1;
            short8 vf = (tt == 0) ? vf0 : (tt == 1) ? vf1 : (tt == 2) ? vf2 : vf3;
            O = __builtin_amdgcn_mfma_f32_32x32x16_bf16(u.s, vf, O, 0, 0, 0);
        }
        if (t + 1 < 16) {
            kf0 = nk0; kf1 = nk1; kf2 = nk2; kf3 = nk3;
            vf0 = nv0; vf1 = nv1; vf2 = nv2; vf3 = nv3;
        }
    }
    sm += __shfl_xor(sm, 32);
    // cross-parity reduction through LDS
    if (wk == 1) {
        #pragma unroll
        for (int j = 0; j < 16; j++) RedO[(wq * 16 + j) * 64 + lane] = O[j];
        if (hi == 0) RedS[wq * 32 + l31] = sm;
    }
    __syncthreads();
    if (wk == 0) {
        #pragma unroll
        for (int j = 0; j < 16; j++) O[j] += RedO[(wq * 16 + j) * 64 + lane];
        sm += RedS[wq * 32 + l31];
        if (hi == 0) smS[wq * 32 + l31] = sm;
    }
    __syncthreads();
    if (wk == 0) {
        const int bb = bh >> 3, hh = bh & 7;
        #pragma unroll
        for (int m = 0; m < 4; m++) {
            float4 sv = *(const float4*)&smS[wq * 32 + 8 * m + 4 * hi];
            #pragma unroll
            for (int i = 0; i < 4; i++) {
                int n = qbase + wq * 32 + 8 * m + 4 * hi + i;
                att[((size_t)(bb * Nseq + n)) * Dm + hh * Hd + l31] =
                    __float2bfloat16(O[4 * m + i] * (1.0f / sv[i]));
            }
        }
    }
}

// ---------------- tail_fused: proj + residual + LN2 + FFN1 + FFN2 ----------
__global__ __launch_bounds__(256, 1) void tail_fused(
    const __hip_bfloat16* __restrict__ att, const __hip_bfloat16* __restrict__ wpT,
    const float* __restrict__ b_proj, const float* __restrict__ x,
    const float* __restrict__ g2, const float* __restrict__ bv2,
    const __hip_bfloat16* __restrict__ w1T, const float* __restrict__ b1,
    const __hip_bfloat16* __restrict__ w2T, const float* __restrict__ b2,
    float* __restrict__ out) {
    __shared__ __align__(16) __hip_bfloat16 WS[2][4][4096];  // 64 KB
    __shared__ __align__(16) __hip_bfloat16 AH[8192];        // att tile, then h2
    __shared__ __align__(16) __hip_bfloat16 PS[16384];       // relu(ffn1) tile
    __shared__ float red[4][32][2];
    __shared__ float muS[32], rsS[32];

    const int tid = threadIdx.x, w = tid >> 6, lane = tid & 63;
    const int lm = lane & 15, lq = lane >> 4;
    const int R0 = blockIdx.x * 32;
    const int c0 = w * 64;
    const int c0f = w * 128;

    {
        const int srow = tid >> 3, ssl = tid & 7;
        #pragma unroll
        for (int kt = 0; kt < 4; kt++)
            gload16(att + (size_t)(R0 + srow) * 256 + kt * 64 + ((ssl ^ (srow & 7)) * 8),
                    AH + kt * 2048 + w * 512);
    }
    #pragma unroll
    for (int ri = 0; ri < 8; ri++) {
        int r = ri * 8 + (lane >> 3), sl = lane & 7;
        gload16(wpT + (size_t)(c0 + r) * 256 + ((sl ^ (r & 7)) * 8), &WS[0][w][ri * 512]);
    }
    __syncthreads();

    short8 aF[2][4][2];
    #pragma unroll
    for (int mf = 0; mf < 2; mf++) {
        int r = mf * 16 + lm;
        #pragma unroll
        for (int kt = 0; kt < 4; kt++)
            #pragma unroll
            for (int ks = 0; ks < 2; ks++)
                aF[mf][kt][ks] = *(const short8*)&AH[kt * 2048 + r * 64 +
                                                    (((ks * 4 + lq) ^ (lm & 7)) * 8)];
    }
    float xr[2][4][4];
    #pragma unroll
    for (int mf = 0; mf < 2; mf++)
        #pragma unroll
        for (int r = 0; r < 4; r++) {
            int row = R0 + mf * 16 + lq * 4 + r;
            #pragma unroll
            for (int nf = 0; nf < 4; nf++)
                xr[mf][nf][r] = x[(size_t)row * 256 + c0 + nf * 16 + lm];
        }

    f32x4 acc[2][4];
    #pragma unroll
    for (int i = 0; i < 2; i++)
        #pragma unroll
        for (int j = 0; j < 4; j++) acc[i][j] = (f32x4){0.f, 0.f, 0.f, 0.f};
    for (int kt = 0; kt < 4; kt++) {
        const int buf = kt & 1;
        if (kt) __syncthreads();
        if (kt + 1 < 4) {
            #pragma unroll
            for (int ri = 0; ri < 8; ri++) {
                int r = ri * 8 + (lane >> 3), sl = lane & 7;
                gload16(wpT + (size_t)(c0 + r) * 256 + (kt + 1) * 64 + ((sl ^ (r & 7)) * 8),
                        &WS[buf ^ 1][w][ri * 512]);
            }
        }
        #pragma unroll
        for (int ks = 0; ks < 2; ks++)
            #pragma unroll
            for (int nf = 0; nf < 4; nf++) {
                int cc = nf * 16 + lm;
                short8 bfr = *(const short8*)&WS[buf][w][cc * 64 + (((ks * 4 + lq) ^ (lm & 7)) * 8)];
                #pragma unroll
                for (int mf = 0; mf < 2; mf++)
                    acc[mf][nf] = __builtin_amdgcn_mfma_f32_16x16x32_bf16(
                        aF[mf][kt][ks], bfr, acc[mf][nf], 0, 0, 0);
            }
    }
    #pragma unroll
    for (int nf = 0; nf < 4; nf++) {
        float bp = b_proj[c0 + nf * 16 + lm];
        #pragma unroll
        for (int mf = 0; mf < 2; mf++)
            #pragma unroll
            for (int r = 0; r < 4; r++) xr[mf][nf][r] += acc[mf][nf][r] + bp;
    }

    #pragma unroll
    for (int mf = 0; mf < 2; mf++)
        #pragma unroll
        for (int r = 0; r < 4; r++) {
            float s = 0.f, ss = 0.f;
            #pragma unroll
            for (int nf = 0; nf < 4; nf++) {
                float v = xr[mf][nf][r];
                s += v; ss += v * v;
            }
            #pragma unroll
            for (int off = 1; off <= 8; off <<= 1) {
                s  += __shfl_xor(s, off);
                ss += __shfl_xor(ss, off);
            }
            if (lm == 0) {
                int row = mf * 16 + lq * 4 + r;
                red[w][row][0] = s;
                red[w][row][1] = ss;
            }
        }
    #pragma unroll
    for (int ri = 0; ri < 8; ri++) {
        int r = ri * 16 + (lane >> 2), sl = lane & 3;
        gload16(w1T + (size_t)(c0f + r) * 256 + ((sl ^ (r & 3)) * 8), &WS[0][w][ri * 512]);
    }
    __syncthreads();
    if (tid < 32) {
        float s = red[0][tid][0] + red[1][tid][0] + red[2][tid][0] + red[3][tid][0];
        float ss = red[0][tid][1] + red[1][tid][1] + red[2][tid][1] + red[3][tid][1];
        float mu = s * (1.0f / 256.0f);
        muS[tid] = mu;
        rsS[tid] = rsqrtf(ss * (1.0f / 256.0f) - mu * mu + EPS_);
    }
    __syncthreads();
    #pragma unroll
    for (int mf = 0; mf < 2; mf++)
        #pragma unroll
        for (int r = 0; r < 4; r++) {
            int row = mf * 16 + lq * 4 + r;
            float mu = muS[row], rs = rsS[row];
            int rw7 = row & 7;
            #pragma unroll
            for (int nf = 0; nf < 4; nf++) {
                int c = c0 + nf * 16 + lm;
                float h = (xr[mf][nf][r] - mu) * rs * g2[c] + bv2[c];
                int slc = nf * 2 + (lm >> 3);
                AH[w * 2048 + row * 64 + ((slc ^ rw7) * 8) + (lm & 7)] = __float2bfloat16(h);
            }
        }
    __syncthreads();

    f32x4 acc2[2][8];
    #pragma unroll
    for (int i = 0; i < 2; i++)
        #pragma unroll
        for (int j = 0; j < 8; j++) acc2[i][j] = (f32x4){0.f, 0.f, 0.f, 0.f};
    for (int kt = 0; kt < 8; kt++) {
        const int buf = kt & 1;
        if (kt) __syncthreads();
        if (kt + 1 < 8) {
            #pragma unroll
            for (int ri = 0; ri < 8; ri++) {
                int r = ri * 16 + (lane >> 2), sl = lane & 3;
                gload16(w1T + (size_t)(c0f + r) * 256 + (kt + 1) * 32 + ((sl ^ (r & 3)) * 8),
                        &WS[buf ^ 1][w][ri * 512]);
            }
        }
        short8 aA[2];
        #pragma unroll
        for (int mf = 0; mf < 2; mf++) {
            int r = mf * 16 + lm;
            aA[mf] = *(const short8*)&AH[(kt >> 1) * 2048 + r * 64 +
                                         ((((kt & 1) * 4 + lq) ^ (lm & 7)) * 8)];
        }
        #pragma unroll
        for (int nf = 0; nf < 8; nf++) {
            int cc = nf * 16 + lm;
            short8 bfr = *(const short8*)&WS[buf][w][cc * 32 + ((lq ^ (lm & 3)) * 8)];
            #pragma unroll
            for (int mf = 0; mf < 2; mf++)
                acc2[mf][nf] = __builtin_amdgcn_mfma_f32_16x16x32_bf16(
                    aA[mf], bfr, acc2[mf][nf], 0, 0, 0);
        }
    }
    #pragma unroll
    for (int ri = 0; ri < 8; ri++) {
        int r = ri * 8 + (lane >> 3), sl = lane & 7;
        gload16(w2T + (size_t)(c0 + r) * 512 + ((sl ^ (r & 7)) * 8), &WS[0][w][ri * 512]);
    }
    #pragma unroll
    for (int nf = 0; nf < 8; nf++) {
        int c = c0f + nf * 16 + lm;
        float bb1 = b1[c];
        int kt8 = w * 2 + (nf >> 2);
        int slc = (nf & 3) * 2 + (lm >> 3);
        #pragma unroll
        for (int mf = 0; mf < 2; mf++)
            #pragma unroll
            for (int r = 0; r < 4; r++) {
                int row = mf * 16 + lq * 4 + r;
                float p = fmaxf(acc2[mf][nf][r] + bb1, 0.f);
                PS[kt8 * 2048 + row * 64 + ((slc ^ (row & 7)) * 8) + (lm & 7)] =
                    __float2bfloat16(p);
            }
    }
    __syncthreads();

    f32x4 acc3[2][4];
    #pragma unroll
    for (int i = 0; i < 2; i++)
        #pragma unroll
        for (int j = 0; j < 4; j++) acc3[i][j] = (f32x4){0.f, 0.f, 0.f, 0.f};
    for (int kt = 0; kt < 8; kt++) {
        const int buf = kt & 1;
        if (kt) __syncthreads();
        if (kt + 1 < 8) {
            #pragma unroll
            for (int ri = 0; ri < 8; ri++) {
                int r = ri * 8 + (lane >> 3), sl = lane & 7;
                gload16(w2T + (size_t)(c0 + r) * 512 + (kt + 1) * 64 + ((sl ^ (r & 7)) * 8),
                        &WS[buf ^ 1][w][ri * 512]);
            }
        }
        #pragma unroll
        for (int ks = 0; ks < 2; ks++) {
            short8 aP[2];
            #pragma unroll
            for (int mf = 0; mf < 2; mf++) {
                int r = mf * 16 + lm;
                aP[mf] = *(const short8*)&PS[kt * 2048 + r * 64 +
                                             (((ks * 4 + lq) ^ (lm & 7)) * 8)];
            }
            #pragma unroll
            for (int nf = 0; nf < 4; nf++) {
                int cc = nf * 16 + lm;
                short8 bfr = *(const short8*)&WS[buf][w][cc * 64 + (((ks * 4 + lq) ^ (lm & 7)) * 8)];
                #pragma unroll
                for (int mf = 0; mf < 2; mf++)
                    acc3[mf][nf] = __builtin_amdgcn_mfma_f32_16x16x32_bf16(
                        aP[mf], bfr, acc3[mf][nf], 0, 0, 0);
            }
        }
    }
    #pragma unroll
    for (int nf = 0; nf < 4; nf++) {
        int c = c0 + nf * 16 + lm;
        float bb2 = b2[c];
        #pragma unroll
        for (int mf = 0; mf < 2; mf++)
            #pragma unroll
            for (int r = 0; r < 4; r++) {
                int row = R0 + mf * 16 + lq * 4 + r;
                out[(size_t)row * 256 + c] = acc3[mf][nf][r] + bb2 + xr[mf][nf][r];
            }
    }
}

extern "C" void kernel_launch(void* const* d_in, const int* in_sizes, int n_in,
                              void* d_out, int out_size, void* d_ws, size_t ws_size,
                              hipStream_t stream) {
    const float* x      = (const float*)d_in[0];
    const float* fcos   = (const float*)d_in[1];
    const float* fsin   = (const float*)d_in[2];
    const float* w_qkv  = (const float*)d_in[3];
    const float* b_qkv  = (const float*)d_in[4];
    const float* w_proj = (const float*)d_in[5];
    const float* b_proj = (const float*)d_in[6];
    const float* ln1_g  = (const float*)d_in[7];
    const float* ln1_b  = (const float*)d_in[8];
    const float* ln2_g  = (const float*)d_in[9];
    const float* ln2_b  = (const float*)d_in[10];
    const float* w1     = (const float*)d_in[11];
    const float* b1     = (const float*)d_in[12];
    const float* w2     = (const float*)d_in[13];
    const float* b2     = (const float*)d_in[14];
    float* out = (float*)d_out;
    char* base = (char*)d_ws;
    const size_t MB = (size_t)1 << 20;

    __hip_bfloat16* h   = (__hip_bfloat16*)(base);            // 4 MB
    __hip_bfloat16* qb  = (__hip_bfloat16*)(base + 4 * MB);
    __hip_bfloat16* kbf = (__hip_bfloat16*)(base + 8 * MB);
    __hip_bfloat16* vtb = (__hip_bfloat16*)(base + 12 * MB);  // transposed [B,H,d,N]
    __hip_bfloat16* att = (__hip_bfloat16*)(base + 16 * MB);
    __hip_bfloat16* wqT = (__hip_bfloat16*)(base + 20 * MB);            // 768x256
    __hip_bfloat16* wpT = (__hip_bfloat16*)(base + 20 * MB + 393216);   // 256x256
    __hip_bfloat16* w1T = (__hip_bfloat16*)(base + 20 * MB + 524288);   // 512x256
    __hip_bfloat16* w2T = (__hip_bfloat16*)(base + 20 * MB + 786432);   // 256x512

    prep_kernel<<<2560, 256, 0, stream>>>(x, ln1_g, ln1_b, h,
                                          w_qkv, w_proj, w1, w2, wqT, wpT, w1T, w2T);
    qkv_mfma<<<dim3(12, 128), 256, 0, stream>>>(h, wqT, b_qkv, fcos, fsin, qb, kbf, vtb);
    attn_mfma<<<dim3(Nseq / 64, Bsz * Hh), 256, 0, stream>>>(qb, kbf, vtb, att);
    tail_fused<<<256, 256, 0, stream>>>(att, wpT, b_proj, x, ln2_g, ln2_b,
                                        w1T, b1, w2T, b2, out);
}

// Round 11
// 166.292 us; speedup vs baseline: 1.0683x; 1.0683x over previous
//
#include <hip/hip_runtime.h>
#include <hip/hip_bf16.h>
#include <math.h>

#define Bsz 4
#define Nseq 2048
#define Dm 256
#define Hh 8
#define Hd 32
#define EPS_ 1e-5f
#define SCALE_ 0.17677669529663687f               // 1/sqrt(32)
#define QSC_ (0.17677669529663687f * 1.4426950408889634f)  // fold log2(e) for exp2

typedef __attribute__((ext_vector_type(8))) short short8;
typedef __attribute__((ext_vector_type(4))) short short4v;
typedef __attribute__((ext_vector_type(4))) float f32x4;
typedef __attribute__((ext_vector_type(16))) float f32x16;

// async global->LDS, 16B per lane. LDS dest = wave-uniform base + lane*16.
__device__ __forceinline__ void gload16(const void* g, void* l) {
    __builtin_amdgcn_global_load_lds(
        (const __attribute__((address_space(1))) void*)g,
        (__attribute__((address_space(3))) void*)l, 16, 0, 0);
}

__device__ __forceinline__ short bf16s(float f) {
    __hip_bfloat16 h = __float2bfloat16(f);
    return *(short*)&h;
}

union FU { float f; unsigned u; };

// pack two fp32 -> (bf16(a) | bf16(b)<<16) via single v_perm_b32 (truncation)
__device__ __forceinline__ int pk2bf(float a, float b) {
    FU ua, ub; ua.f = a; ub.f = b;
    return (int)__builtin_amdgcn_perm(ub.u, ua.u, 0x07060302u);
}

union I4S8 { int i[4]; short8 s; };

// ---------------- prep: LN1 (bid<2048) + weight transpose (bid>=2048) ------
__global__ __launch_bounds__(256) void prep_kernel(
    const float* __restrict__ x, const float* __restrict__ g1,
    const float* __restrict__ b1v, __hip_bfloat16* __restrict__ hout,
    const float* __restrict__ s0, const float* __restrict__ s1,
    const float* __restrict__ s2, const float* __restrict__ s3,
    __hip_bfloat16* __restrict__ d0, __hip_bfloat16* __restrict__ d1,
    __hip_bfloat16* __restrict__ d2, __hip_bfloat16* __restrict__ d3) {
    __shared__ float t[32][33];
    if (blockIdx.x < 2048) {
        int row  = blockIdx.x * 4 + (threadIdx.x >> 6);
        int lane = threadIdx.x & 63;
        const float* xr = x + (size_t)row * Dm;
        float4 v = *(const float4*)(xr + lane * 4);
        float s  = v.x + v.y + v.z + v.w;
        float ss = v.x * v.x + v.y * v.y + v.z * v.z + v.w * v.w;
        #pragma unroll
        for (int off = 32; off; off >>= 1) {
            s  += __shfl_xor(s, off);
            ss += __shfl_xor(ss, off);
        }
        float mu  = s * (1.0f / Dm);
        float var = ss * (1.0f / Dm) - mu * mu;
        float rs  = rsqrtf(var + EPS_);
        float4 gv = *(const float4*)(g1 + lane * 4);
        float4 bv = *(const float4*)(b1v + lane * 4);
        short4v o4 = { bf16s((v.x - mu) * rs * gv.x + bv.x),
                       bf16s((v.y - mu) * rs * gv.y + bv.y),
                       bf16s((v.z - mu) * rs * gv.z + bv.z),
                       bf16s((v.w - mu) * rs * gv.w + bv.w) };
        *(short4v*)(hout + (size_t)row * Dm + lane * 4) = o4;
        return;
    }
    int bid = blockIdx.x - 2048;
    const float* src; __hip_bfloat16* dst; int K, N, tb;
    if (bid < 192)      { src = s0; dst = d0; K = 256; N = 768; tb = bid; }
    else if (bid < 256) { src = s1; dst = d1; K = 256; N = 256; tb = bid - 192; }
    else if (bid < 384) { src = s2; dst = d2; K = 256; N = 512; tb = bid - 256; }
    else                { src = s3; dst = d3; K = 512; N = 256; tb = bid - 384; }
    int tn = N >> 5;
    int k0 = (tb / tn) * 32, n0 = (tb % tn) * 32;
    int c = threadIdx.x & 31, r0 = threadIdx.x >> 5;
    #pragma unroll
    for (int i = 0; i < 4; i++) {
        int r = r0 + i * 8;
        t[r][c] = src[(size_t)(k0 + r) * N + n0 + c];
    }
    __syncthreads();
    #pragma unroll
    for (int i = 0; i < 4; i++) {
        int n = r0 + i * 8;
        dst[(size_t)(n0 + n) * K + k0 + c] = __float2bfloat16(t[c][n]);
    }
}

// ---------------- QKV: BK=64 dbuf MFMA GEMM + bias/RoPE/scatter ------------
__global__ __launch_bounds__(256) void qkv_mfma(const __hip_bfloat16* __restrict__ A,
                                                const __hip_bfloat16* __restrict__ Wt,
                                                const float* __restrict__ bias,
                                                const float* __restrict__ fcos,
                                                const float* __restrict__ fsin,
                                                __hip_bfloat16* __restrict__ qout,
                                                __hip_bfloat16* __restrict__ kout,
                                                __hip_bfloat16* __restrict__ vt) {
    const int K = 256;
    __shared__ __align__(16) __hip_bfloat16 As[2][64 * 64];
    __shared__ __align__(16) __hip_bfloat16 Bs[2][64 * 64];
    const int tid = threadIdx.x, w = tid >> 6, lane = tid & 63;
    const int lm = lane & 15, lq = lane >> 4;
    const int bm = blockIdx.y * 64, bn = blockIdx.x * 64;
    f32x4 acc[4];
    #pragma unroll
    for (int j = 0; j < 4; j++) acc[j] = (f32x4){0.f, 0.f, 0.f, 0.f};

    const int sr = tid >> 3, ssl = tid & 7;
    const int sgk = (ssl ^ (sr & 7)) * 8;
    const int sr2 = 32 + sr;
    const int sgk2 = (ssl ^ (sr2 & 7)) * 8;

    gload16(A + (size_t)(bm + sr) * K + sgk, &As[0][w * 512]);
    gload16(A + (size_t)(bm + sr2) * K + sgk2, &As[0][2048 + w * 512]);
    gload16(Wt + (size_t)(bn + sr) * K + sgk, &Bs[0][w * 512]);
    gload16(Wt + (size_t)(bn + sr2) * K + sgk2, &Bs[0][2048 + w * 512]);

    const int arow = w * 16 + lm;
    const int ar7 = arow & 7;
    for (int t = 0; t < K / 64; t++) {
        const int buf = t & 1;
        __syncthreads();
        if (t + 1 < K / 64) {
            int k0 = (t + 1) * 64;
            gload16(A + (size_t)(bm + sr) * K + k0 + sgk, &As[buf ^ 1][w * 512]);
            gload16(A + (size_t)(bm + sr2) * K + k0 + sgk2, &As[buf ^ 1][2048 + w * 512]);
            gload16(Wt + (size_t)(bn + sr) * K + k0 + sgk, &Bs[buf ^ 1][w * 512]);
            gload16(Wt + (size_t)(bn + sr2) * K + k0 + sgk2, &Bs[buf ^ 1][2048 + w * 512]);
        }
        #pragma unroll
        for (int ks = 0; ks < 2; ks++) {
            short8 a = *(const short8*)&As[buf][arow * 64 + (((ks * 4 + lq) ^ ar7) * 8)];
            #pragma unroll
            for (int nf = 0; nf < 4; nf++) {
                int cc = nf * 16 + lm;
                short8 bfr = *(const short8*)&Bs[buf][cc * 64 + (((ks * 4 + lq) ^ (cc & 7)) * 8)];
                acc[nf] = __builtin_amdgcn_mfma_f32_16x16x32_bf16(a, bfr, acc[nf], 0, 0, 0);
            }
        }
    }
    const int seg = bn >> 8;  // 0=q 1=k 2=v, uniform per block
    #pragma unroll
    for (int nf = 0; nf < 4; nf++) {
        int cg = bn + nf * 16 + lm;
        int hh = (cg & 255) >> 5;
        int dd = (nf & 1) * 16 + lm;
        int i0 = dd >> 1;
        float bi = bias[cg];
        #pragma unroll
        for (int r = 0; r < 4; r++) {
            int rg = bm + w * 16 + lq * 4 + r;
            int bb = rg >> 11, n = rg & (Nseq - 1);
            float v = acc[nf][r] + bi;
            if (seg == 2) {
                vt[(((size_t)(bb * Hh + hh)) * Hd + dd) * Nseq + n] = __float2bfloat16(v);
            } else {
                float vp = __shfl_xor(v, 1);
                float cs = fcos[n * 16 + i0], sn = fsin[n * 16 + i0];
                float outv = (dd & 1) ? (vp * sn + v * cs) : (v * cs - vp * sn);
                if (seg == 0) outv *= QSC_;
                __hip_bfloat16* dst = (seg == 0) ? qout : kout;
                dst[(((size_t)(bb * Hh + hh)) * Nseq + n) * Hd + dd] = __float2bfloat16(outv);
            }
        }
    }
}

// ---------------- Flash attention: 32-row blocks, 4-way key split ----------
// Block = 32 q rows, 4 waves; wave w owns all 32 rows, key chunks 4t+w
// (t=0..7). K chunks -> registers (coalesced: lane stride 64B); V -> wave-
// private SINGLE LDS buffer via gload16 (coalesced along keys). Sync: manual
// vmcnt(4) before PV reads (FIFO: 4 newer K-loads allowed, V drained);
// lgkmcnt(0) before V overwrite. Grid 2048 blocks, LDS ~18.9 KB -> 7
// blocks/CU (vs R9's 4) for VALU packing. Final 4-way reduction aliased
// into the dead V region.
__global__ __launch_bounds__(256) void attn_mfma(const __hip_bfloat16* __restrict__ q,
                                                 const __hip_bfloat16* __restrict__ k,
                                                 const __hip_bfloat16* __restrict__ vt,
                                                 __hip_bfloat16* __restrict__ att) {
    __shared__ __align__(16) char smem[2048 + 16384 + 512];
    __hip_bfloat16* Qs = (__hip_bfloat16*)smem;            // 32x32 = 2 KB
    __hip_bfloat16* Vw = (__hip_bfloat16*)(smem + 2048);   // [wave][32*64] 16 KB
    float* RedO = (float*)(smem + 2048);                   // alias Vw (12 KB used)
    float* RedS = (float*)(smem + 2048 + 16384);           // 96 floats
    float* smS  = (float*)(smem + 2048 + 16384 + 384);     // 32 floats

    const int tid = threadIdx.x, w = tid >> 6, lane = tid & 63;
    const int l31 = lane & 31, hi = lane >> 5;
    const int bh = blockIdx.y, qbase = blockIdx.x * 32;
    const __hip_bfloat16* qp = q + ((size_t)bh * Nseq + qbase) * Hd;
    const __hip_bfloat16* kp = k + (size_t)bh * Nseq * Hd;
    const __hip_bfloat16* vp = vt + (size_t)bh * Hd * Nseq;

    if (w < 2) {   // Q cooperative stage: 32 rows x 32, 4-slot xor swizzle
        int r = tid >> 2, sl = tid & 3;
        gload16(qp + r * 32 + ((sl ^ (r & 3)) * 8), Qs + w * 512);
    }
    // V chunk w -> wave-private single buffer (layout [d][key], 8-slot swz)
    __hip_bfloat16* myV = Vw + w * 2048;
    const int vd = (lane >> 3) & 7, vs = lane & 7;
    const int szv = (vs ^ vd) * 8;
    #pragma unroll
    for (int i = 0; i < 4; i++)
        gload16(vp + (size_t)(i * 8 + vd) * Nseq + w * 64 + szv, myV + i * 512);
    // K chunk w -> registers (A-frag: K[64c+key][d], lane stride 64B)
    const __hip_bfloat16* kb = kp + (size_t)l31 * Hd + hi * 8;
    short8 kf0 = *(const short8*)(kb + w * 2048);
    short8 kf1 = *(const short8*)(kb + w * 2048 + 16);
    short8 kf2 = *(const short8*)(kb + w * 2048 + 1024);
    short8 kf3 = *(const short8*)(kb + w * 2048 + 1040);
    __syncthreads();   // Q + V(0) visible (full vmcnt drain)

    short8 qf0 = *(const short8*)&Qs[l31 * 32 + ((hi ^ (l31 & 3)) * 8)];
    short8 qf1 = *(const short8*)&Qs[l31 * 32 + (((2 + hi) ^ (l31 & 3)) * 8)];

    f32x16 O;
    #pragma unroll
    for (int i = 0; i < 16; i++) O[i] = 0.f;
    float sm = 0.f;

    for (int t = 0; t < 8; t++) {
        short8 nk0, nk1, nk2, nk3;
        if (t + 1 < 8) {
            const int c = 4 * (t + 1) + w;
            const __hip_bfloat16* kbn = kb + (size_t)c * 2048;
            nk0 = *(const short8*)(kbn);
            nk1 = *(const short8*)(kbn + 16);
            nk2 = *(const short8*)(kbn + 1024);
            nk3 = *(const short8*)(kbn + 1040);
        }
        // S^T = K·Q^T (keys 0-31 in St0, 32-63 in St1); K/Q in regs
        f32x16 St0, St1;
        #pragma unroll
        for (int i = 0; i < 16; i++) { St0[i] = 0.f; St1[i] = 0.f; }
        St0 = __builtin_amdgcn_mfma_f32_32x32x16_bf16(kf0, qf0, St0, 0, 0, 0);
        St0 = __builtin_amdgcn_mfma_f32_32x32x16_bf16(kf1, qf1, St0, 0, 0, 0);
        St1 = __builtin_amdgcn_mfma_f32_32x32x16_bf16(kf2, qf0, St1, 0, 0, 0);
        St1 = __builtin_amdgcn_mfma_f32_32x32x16_bf16(kf3, qf1, St1, 0, 0, 0);
        // exp2 + single-instruction pair pack
        int pk0[8], pk1[8];
        #pragma unroll
        for (int p = 0; p < 8; p++) {
            float a = __builtin_amdgcn_exp2f(St0[2 * p]);
            float b = __builtin_amdgcn_exp2f(St0[2 * p + 1]);
            sm += a + b;
            pk0[p] = pk2bf(a, b);
        }
        #pragma unroll
        for (int p = 0; p < 8; p++) {
            float a = __builtin_amdgcn_exp2f(St1[2 * p]);
            float b = __builtin_amdgcn_exp2f(St1[2 * p + 1]);
            sm += a + b;
            pk1[p] = pk2bf(a, b);
        }
        // V(t) resident: only the 4 newer K(t+1) loads may stay outstanding
        if (t + 1 < 8) asm volatile("s_waitcnt vmcnt(4)" ::: "memory");
        else           asm volatile("s_waitcnt vmcnt(0)" ::: "memory");
        #pragma unroll
        for (int tt = 0; tt < 4; tt++) {
            const int* PK = (tt >> 1) ? pk1 : pk0;
            const int base = 4 * (tt & 1);
            int keep0 = hi ? PK[base + 2] : PK[base + 0];
            int keep1 = hi ? PK[base + 3] : PK[base + 1];
            int send0 = hi ? PK[base + 0] : PK[base + 2];
            int send1 = hi ? PK[base + 1] : PK[base + 3];
            int x0 = __shfl_xor(send0, 32);
            int x1 = __shfl_xor(send1, 32);
            I4S8 u;
            u.i[0] = hi ? x0 : keep0;
            u.i[1] = hi ? x1 : keep1;
            u.i[2] = hi ? keep0 : x0;
            u.i[3] = hi ? keep1 : x1;
            short8 vf = *(const short8*)&myV[l31 * 64 + (((2 * tt + hi) ^ (l31 & 7)) * 8)];
            O = __builtin_amdgcn_mfma_f32_32x32x16_bf16(u.s, vf, O, 0, 0, 0);
        }
        if (t + 1 < 8) {
            // prior ds_reads delivered before overwriting the single buffer
            asm volatile("s_waitcnt lgkmcnt(0)" ::: "memory");
            const int c = 4 * (t + 1) + w;
            #pragma unroll
            for (int i = 0; i < 4; i++)
                gload16(vp + (size_t)(i * 8 + vd) * Nseq + c * 64 + szv, myV + i * 512);
            kf0 = nk0; kf1 = nk1; kf2 = nk2; kf3 = nk3;
        }
    }
    sm += __shfl_xor(sm, 32);
    __syncthreads();   // all waves out of the loop; Vw dead -> RedO aliases it
    if (w) {
        #pragma unroll
        for (int j = 0; j < 16; j++) RedO[(w - 1) * 1024 + j * 64 + lane] = O[j];
        if (hi == 0) RedS[(w - 1) * 32 + l31] = sm;
    }
    __syncthreads();
    if (w == 0) {
        #pragma unroll
        for (int j = 0; j < 16; j++)
            O[j] += RedO[j * 64 + lane] + RedO[1024 + j * 64 + lane] +
                    RedO[2048 + j * 64 + lane];
        sm += RedS[l31] + RedS[32 + l31] + RedS[64 + l31];
        if (hi == 0) smS[l31] = sm;
        __builtin_amdgcn_s_waitcnt(0);  // lgkm drain before smS readback
    }
    __syncthreads();
    if (w == 0) {
        const int bb = bh >> 3, hh = bh & 7;
        #pragma unroll
        for (int m = 0; m < 4; m++) {
            float4 sv = *(const float4*)&smS[8 * m + 4 * hi];
            #pragma unroll
            for (int i = 0; i < 4; i++) {
                int n = qbase + 8 * m + 4 * hi + i;
                att[((size_t)(bb * Nseq + n)) * Dm + hh * Hd + l31] =
                    __float2bfloat16(O[4 * m + i] * (1.0f / sv[i]));
            }
        }
    }
}

// ---------------- tail_fused: proj + residual + LN2 + FFN1 + FFN2 ----------
__global__ __launch_bounds__(256, 1) void tail_fused(
    const __hip_bfloat16* __restrict__ att, const __hip_bfloat16* __restrict__ wpT,
    const float* __restrict__ b_proj, const float* __restrict__ x,
    const float* __restrict__ g2, const float* __restrict__ bv2,
    const __hip_bfloat16* __restrict__ w1T, const float* __restrict__ b1,
    const __hip_bfloat16* __restrict__ w2T, const float* __restrict__ b2,
    float* __restrict__ out) {
    __shared__ __align__(16) __hip_bfloat16 WS[2][4][4096];  // 64 KB
    __shared__ __align__(16) __hip_bfloat16 AH[8192];        // att tile, then h2
    __shared__ __align__(16) __hip_bfloat16 PS[16384];       // relu(ffn1) tile
    __shared__ float red[4][32][2];
    __shared__ float muS[32], rsS[32];

    const int tid = threadIdx.x, w = tid >> 6, lane = tid & 63;
    const int lm = lane & 15, lq = lane >> 4;
    const int R0 = blockIdx.x * 32;
    const int c0 = w * 64;
    const int c0f = w * 128;

    {
        const int srow = tid >> 3, ssl = tid & 7;
        #pragma unroll
        for (int kt = 0; kt < 4; kt++)
            gload16(att + (size_t)(R0 + srow) * 256 + kt * 64 + ((ssl ^ (srow & 7)) * 8),
                    AH + kt * 2048 + w * 512);
    }
    #pragma unroll
    for (int ri = 0; ri < 8; ri++) {
        int r = ri * 8 + (lane >> 3), sl = lane & 7;
        gload16(wpT + (size_t)(c0 + r) * 256 + ((sl ^ (r & 7)) * 8), &WS[0][w][ri * 512]);
    }
    __syncthreads();

    short8 aF[2][4][2];
    #pragma unroll
    for (int mf = 0; mf < 2; mf++) {
        int r = mf * 16 + lm;
        #pragma unroll
        for (int kt = 0; kt < 4; kt++)
            #pragma unroll
            for (int ks = 0; ks < 2; ks++)
                aF[mf][kt][ks] = *(const short8*)&AH[kt * 2048 + r * 64 +
                                                    (((ks * 4 + lq) ^ (lm & 7)) * 8)];
    }
    float xr[2][4][4];
    #pragma unroll
    for (int mf = 0; mf < 2; mf++)
        #pragma unroll
        for (int r = 0; r < 4; r++) {
            int row = R0 + mf * 16 + lq * 4 + r;
            #pragma unroll
            for (int nf = 0; nf < 4; nf++)
                xr[mf][nf][r] = x[(size_t)row * 256 + c0 + nf * 16 + lm];
        }

    f32x4 acc[2][4];
    #pragma unroll
    for (int i = 0; i < 2; i++)
        #pragma unroll
        for (int j = 0; j < 4; j++) acc[i][j] = (f32x4){0.f, 0.f, 0.f, 0.f};
    for (int kt = 0; kt < 4; kt++) {
        const int buf = kt & 1;
        if (kt) __syncthreads();
        if (kt + 1 < 4) {
            #pragma unroll
            for (int ri = 0; ri < 8; ri++) {
                int r = ri * 8 + (lane >> 3), sl = lane & 7;
                gload16(wpT + (size_t)(c0 + r) * 256 + (kt + 1) * 64 + ((sl ^ (r & 7)) * 8),
                        &WS[buf ^ 1][w][ri * 512]);
            }
        }
        #pragma unroll
        for (int ks = 0; ks < 2; ks++)
            #pragma unroll
            for (int nf = 0; nf < 4; nf++) {
                int cc = nf * 16 + lm;
                short8 bfr = *(const short8*)&WS[buf][w][cc * 64 + (((ks * 4 + lq) ^ (lm & 7)) * 8)];
                #pragma unroll
                for (int mf = 0; mf < 2; mf++)
                    acc[mf][nf] = __builtin_amdgcn_mfma_f32_16x16x32_bf16(
                        aF[mf][kt][ks], bfr, acc[mf][nf], 0, 0, 0);
            }
    }
    #pragma unroll
    for (int nf = 0; nf < 4; nf++) {
        float bp = b_proj[c0 + nf * 16 + lm];
        #pragma unroll
        for (int mf = 0; mf < 2; mf++)
            #pragma unroll
            for (int r = 0; r < 4; r++) xr[mf][nf][r] += acc[mf][nf][r] + bp;
    }

    #pragma unroll
    for (int mf = 0; mf < 2; mf++)
        #pragma unroll
        for (int r = 0; r < 4; r++) {
            float s = 0.f, ss = 0.f;
            #pragma unroll
            for (int nf = 0; nf < 4; nf++) {
                float v = xr[mf][nf][r];
                s += v; ss += v * v;
            }
            #pragma unroll
            for (int off = 1; off <= 8; off <<= 1) {
                s  += __shfl_xor(s, off);
                ss += __shfl_xor(ss, off);
            }
            if (lm == 0) {
                int row = mf * 16 + lq * 4 + r;
                red[w][row][0] = s;
                red[w][row][1] = ss;
            }
        }
    #pragma unroll
    for (int ri = 0; ri < 8; ri++) {
        int r = ri * 16 + (lane >> 2), sl = lane & 3;
        gload16(w1T + (size_t)(c0f + r) * 256 + ((sl ^ (r & 3)) * 8), &WS[0][w][ri * 512]);
    }
    __syncthreads();
    if (tid < 32) {
        float s = red[0][tid][0] + red[1][tid][0] + red[2][tid][0] + red[3][tid][0];
        float ss = red[0][tid][1] + red[1][tid][1] + red[2][tid][1] + red[3][tid][1];
        float mu = s * (1.0f / 256.0f);
        muS[tid] = mu;
        rsS[tid] = rsqrtf(ss * (1.0f / 256.0f) - mu * mu + EPS_);
    }
    __syncthreads();
    #pragma unroll
    for (int mf = 0; mf < 2; mf++)
        #pragma unroll
        for (int r = 0; r < 4; r++) {
            int row = mf * 16 + lq * 4 + r;
            float mu = muS[row], rs = rsS[row];
            int rw7 = row & 7;
            #pragma unroll
            for (int nf = 0; nf < 4; nf++) {
                int c = c0 + nf * 16 + lm;
                float h = (xr[mf][nf][r] - mu) * rs * g2[c] + bv2[c];
                int slc = nf * 2 + (lm >> 3);
                AH[w * 2048 + row * 64 + ((slc ^ rw7) * 8) + (lm & 7)] = __float2bfloat16(h);
            }
        }
    __syncthreads();

    f32x4 acc2[2][8];
    #pragma unroll
    for (int i = 0; i < 2; i++)
        #pragma unroll
        for (int j = 0; j < 8; j++) acc2[i][j] = (f32x4){0.f, 0.f, 0.f, 0.f};
    for (int kt = 0; kt < 8; kt++) {
        const int buf = kt & 1;
        if (kt) __syncthreads();
        if (kt + 1 < 8) {
            #pragma unroll
            for (int ri = 0; ri < 8; ri++) {
                int r = ri * 16 + (lane >> 2), sl = lane & 3;
                gload16(w1T + (size_t)(c0f + r) * 256 + (kt + 1) * 32 + ((sl ^ (r & 3)) * 8),
                        &WS[buf ^ 1][w][ri * 512]);
            }
        }
        short8 aA[2];
        #pragma unroll
        for (int mf = 0; mf < 2; mf++) {
            int r = mf * 16 + lm;
            aA[mf] = *(const short8*)&AH[(kt >> 1) * 2048 + r * 64 +
                                         ((((kt & 1) * 4 + lq) ^ (lm & 7)) * 8)];
        }
        #pragma unroll
        for (int nf = 0; nf < 8; nf++) {
            int cc = nf * 16 + lm;
            short8 bfr = *(const short8*)&WS[buf][w][cc * 32 + ((lq ^ (lm & 3)) * 8)];
            #pragma unroll
            for (int mf = 0; mf < 2; mf++)
                acc2[mf][nf] = __builtin_amdgcn_mfma_f32_16x16x32_bf16(
                    aA[mf], bfr, acc2[mf][nf], 0, 0, 0);
        }
    }
    #pragma unroll
    for (int ri = 0; ri < 8; ri++) {
        int r = ri * 8 + (lane >> 3), sl = lane & 7;
        gload16(w2T + (size_t)(c0 + r) * 512 + ((sl ^ (r & 7)) * 8), &WS[0][w][ri * 512]);
    }
    #pragma unroll
    for (int nf = 0; nf < 8; nf++) {
        int c = c0f + nf * 16 + lm;
        float bb1 = b1[c];
        int kt8 = w * 2 + (nf >> 2);
        int slc = (nf & 3) * 2 + (lm >> 3);
        #pragma unroll
        for (int mf = 0; mf < 2; mf++)
            #pragma unroll
            for (int r = 0; r < 4; r++) {
                int row = mf * 16 + lq * 4 + r;
                float p = fmaxf(acc2[mf][nf][r] + bb1, 0.f);
                PS[kt8 * 2048 + row * 64 + ((slc ^ (row & 7)) * 8) + (lm & 7)] =
                    __float2bfloat16(p);
            }
    }
    __syncthreads();

    f32x4 acc3[2][4];
    #pragma unroll
    for (int i = 0; i < 2; i++)
        #pragma unroll
        for (int j = 0; j < 4; j++) acc3[i][j] = (f32x4){0.f, 0.f, 0.f, 0.f};
    for (int kt = 0; kt < 8; kt++) {
        const int buf = kt & 1;
        if (kt) __syncthreads();
        if (kt + 1 < 8) {
            #pragma unroll
            for (int ri = 0; ri < 8; ri++) {
                int r = ri * 8 + (lane >> 3), sl = lane & 7;
                gload16(w2T + (size_t)(c0 + r) * 512 + (kt + 1) * 64 + ((sl ^ (r & 7)) * 8),
                        &WS[buf ^ 1][w][ri * 512]);
            }
        }
        #pragma unroll
        for (int ks = 0; ks < 2; ks++) {
            short8 aP[2];
            #pragma unroll
            for (int mf = 0; mf < 2; mf++) {
                int r = mf * 16 + lm;
                aP[mf] = *(const short8*)&PS[kt * 2048 + r * 64 +
                                             (((ks * 4 + lq) ^ (lm & 7)) * 8)];
            }
            #pragma unroll
            for (int nf = 0; nf < 4; nf++) {
                int cc = nf * 16 + lm;
                short8 bfr = *(const short8*)&WS[buf][w][cc * 64 + (((ks * 4 + lq) ^ (lm & 7)) * 8)];
                #pragma unroll
                for (int mf = 0; mf < 2; mf++)
                    acc3[mf][nf] = __builtin_amdgcn_mfma_f32_16x16x32_bf16(
                        aP[mf], bfr, acc3[mf][nf], 0, 0, 0);
            }
        }
    }
    #pragma unroll
    for (int nf = 0; nf < 4; nf++) {
        int c = c0 + nf * 16 + lm;
        float bb2 = b2[c];
        #pragma unroll
        for (int mf = 0; mf < 2; mf++)
            #pragma unroll
            for (int r = 0; r < 4; r++) {
                int row = R0 + mf * 16 + lq * 4 + r;
                out[(size_t)row * 256 + c] = acc3[mf][nf][r] + bb2 + xr[mf][nf][r];
            }
    }
}

extern "C" void kernel_launch(void* const* d_in, const int* in_sizes, int n_in,
                              void* d_out, int out_size, void* d_ws, size_t ws_size,
                              hipStream_t stream) {
    const float* x      = (const float*)d_in[0];
    const float* fcos   = (const float*)d_in[1];
    const float* fsin   = (const float*)d_in[2];
    const float* w_qkv  = (const float*)d_in[3];
    const float* b_qkv  = (const float*)d_in[4];
    const float* w_proj = (const float*)d_in[5];
    const float* b_proj = (const float*)d_in[6];
    const float* ln1_g  = (const float*)d_in[7];
    const float* ln1_b  = (const float*)d_in[8];
    const float* ln2_g  = (const float*)d_in[9];
    const float* ln2_b  = (const float*)d_in[10];
    const float* w1     = (const float*)d_in[11];
    const float* b1     = (const float*)d_in[12];
    const float* w2     = (const float*)d_in[13];
    const float* b2     = (const float*)d_in[14];
    float* out = (float*)d_out;
    char* base = (char*)d_ws;
    const size_t MB = (size_t)1 << 20;

    __hip_bfloat16* h   = (__hip_bfloat16*)(base);            // 4 MB
    __hip_bfloat16* qb  = (__hip_bfloat16*)(base + 4 * MB);
    __hip_bfloat16* kbf = (__hip_bfloat16*)(base + 8 * MB);
    __hip_bfloat16* vtb = (__hip_bfloat16*)(base + 12 * MB);  // transposed [B,H,d,N]
    __hip_bfloat16* att = (__hip_bfloat16*)(base + 16 * MB);
    __hip_bfloat16* wqT = (__hip_bfloat16*)(base + 20 * MB);            // 768x256
    __hip_bfloat16* wpT = (__hip_bfloat16*)(base + 20 * MB + 393216);   // 256x256
    __hip_bfloat16* w1T = (__hip_bfloat16*)(base + 20 * MB + 524288);   // 512x256
    __hip_bfloat16* w2T = (__hip_bfloat16*)(base + 20 * MB + 786432);   // 256x512

    prep_kernel<<<2560, 256, 0, stream>>>(x, ln1_g, ln1_b, h,
                                          w_qkv, w_proj, w1, w2, wqT, wpT, w1T, w2T);
    qkv_mfma<<<dim3(12, 128), 256, 0, stream>>>(h, wqT, b_qkv, fcos, fsin, qb, kbf, vtb);
    attn_mfma<<<dim3(Nseq / 32, Bsz * Hh), 256, 0, stream>>>(qb, kbf, vtb, att);
    tail_fused<<<256, 256, 0, stream>>>(att, wpT, b_proj, x, ln2_g, ln2_b,
                                        w1T, b1, w2T, b2, out);
}